// Round 4
// baseline (1170.045 us; speedup 1.0000x reference)
//
#include <hip/hip_runtime.h>
#include <hip/hip_bf16.h>

// Problem constants
// B=512, N(L)=256, D=128, DI=256, NL=4, NS=16, KC=4, DH=64, H=64
// M = B*N = 131072 tokens

typedef __bf16 bf16_8 __attribute__((ext_vector_type(8)));
typedef float  f32_4  __attribute__((ext_vector_type(4)));

#define LDKC 72   // 64 K-chunk + 8 pad (row stride 144B, multiple of 16B)

// ---------------------------------------------------------------------------
// prep: convert W_in (4*512*128), W_out (4*128*256), imp_W1 (64*128) fp32->bf16
__global__ __launch_bounds__(256) void prep_kernel(const float* __restrict__ win,
                                                   const float* __restrict__ wout,
                                                   const float* __restrict__ w1,
                                                   __bf16* __restrict__ win16,
                                                   __bf16* __restrict__ wout16,
                                                   __bf16* __restrict__ w116) {
    int i = blockIdx.x * 256 + threadIdx.x;
    if (i < 4 * 512 * 128) win16[i] = (__bf16)win[i];
    if (i < 4 * 128 * 256) wout16[i] = (__bf16)wout[i];
    if (i < 64 * 128)      w116[i]  = (__bf16)w1[i];
}

// ---------------------------------------------------------------------------
// build_T: T[layer][l][j] = Kk[l-j] + (l==j)*Dp, 0 for j>l  (bf16, 256x256/layer)
// Kk[d] = sum_n Cp[n]*dB[n]*exp(e_n*d),  e_n = clamp(dt*A_n, -10, 10)
__global__ __launch_bounds__(256) void build_T_kernel(const float* __restrict__ Bp,
                                                      const float* __restrict__ Cp,
                                                      const float* __restrict__ ldt,
                                                      const float* __restrict__ Dpv,
                                                      __bf16* __restrict__ Tg) {
    int layer = blockIdx.y, l = blockIdx.x, j = threadIdx.x;
    int d = l - j;
    float val = 0.0f;
    if (d >= 0) {
        float dt = expf(ldt[layer]);
        dt = fminf(fmaxf(dt, 1e-4f), 1.0f);
        #pragma unroll
        for (int n = 0; n < 16; ++n) {
            float A = -(float)(n + 1);
            float e = fminf(fmaxf(dt * A, -10.0f), 10.0f);
            float dA = expf(e);
            float dB = (dA - 1.0f) / A * Bp[layer * 16 + n];
            val += Cp[layer * 16 + n] * dB * expf(e * (float)d);
        }
        if (d == 0) val += Dpv[layer];
    }
    Tg[layer * 65536 + l * 256 + j] = (__bf16)val;
}

// ---------------------------------------------------------------------------
// x = init + pos (broadcast over batch)
__global__ __launch_bounds__(256) void add_pos_kernel(const float4* __restrict__ a,
                                                      const float4* __restrict__ p,
                                                      float4* __restrict__ x) {
    int i = blockIdx.x * 256 + threadIdx.x;       // 4194304 total float4
    float4 u = a[i];
    float4 v = p[i & 8191];                       // N*D/4 = 8192 per batch
    x[i] = make_float4(u.x + v.x, u.y + v.y, u.z + v.z, u.w + v.w);
}

// ---------------------------------------------------------------------------
// LayerNorm: x fp32 -> h bf16.  One wave per token (D=128, 2 elems/lane).
__global__ __launch_bounds__(256) void ln_kernel(const float* __restrict__ x,
                                                 const float* __restrict__ g,
                                                 const float* __restrict__ bta,
                                                 __bf16* __restrict__ h) {
    int wave = threadIdx.x >> 6, lane = threadIdx.x & 63;
    long tok = (long)blockIdx.x * 4 + wave;
    const float* xr = x + tok * 128;
    float v0 = xr[lane], v1 = xr[lane + 64];
    float s = v0 + v1, ss = v0 * v0 + v1 * v1;
    #pragma unroll
    for (int o = 32; o; o >>= 1) { s += __shfl_xor(s, o); ss += __shfl_xor(ss, o); }
    float m = s * (1.0f / 128.0f);
    float var = ss * (1.0f / 128.0f) - m * m;
    float r = rsqrtf(var + 1e-5f);
    __bf16* hr = h + tok * 128;
    hr[lane]      = (__bf16)((v0 - m) * r * g[lane]      + bta[lane]);
    hr[lane + 64] = (__bf16)((v1 - m) * r * g[lane + 64] + bta[lane + 64]);
}

// ---------------------------------------------------------------------------
// GEMM1: xz[m,n] = sum_k h[m,k] * Win[n,k]; M=131072, N=512, K=128.
__global__ __launch_bounds__(256) void gemm1_kernel(const __bf16* __restrict__ hmat,
                                                    const __bf16* __restrict__ win,
                                                    __bf16* __restrict__ xp,
                                                    __bf16* __restrict__ z) {
    __shared__ __bf16 As[128 * LDKC];
    __shared__ __bf16 Bs[128 * LDKC];
    int tid = threadIdx.x;
    long m0 = (long)blockIdx.x * 128;
    int n0 = blockIdx.y * 128;
    int wave = tid >> 6, lane = tid & 63;
    int wm = wave >> 1, wn = wave & 1;
    int lrow = lane & 15, lk = (lane >> 4) * 8;
    f32_4 acc[4][4] = {};

    for (int kc = 0; kc < 2; ++kc) {
        const __bf16* asrc = hmat + m0 * 128 + kc * 64;
        const __bf16* bsrc = win + (long)n0 * 128 + kc * 64;
        #pragma unroll
        for (int i = 0; i < 4; ++i) {
            int idx = tid + i * 256;          // 0..1023
            int row = idx >> 3, c4 = idx & 7; // 8 uint4 per 64-elem row
            uint4 va = *(const uint4*)(asrc + row * 128 + c4 * 8);
            *(uint4*)(As + row * LDKC + c4 * 8) = va;
            uint4 vb = *(const uint4*)(bsrc + row * 128 + c4 * 8);
            *(uint4*)(Bs + row * LDKC + c4 * 8) = vb;
        }
        __syncthreads();
        #pragma unroll
        for (int kk = 0; kk < 64; kk += 32) {
            bf16_8 a[4], b[4];
            #pragma unroll
            for (int mt = 0; mt < 4; ++mt)
                a[mt] = *(const bf16_8*)(As + (wm * 64 + mt * 16 + lrow) * LDKC + kk + lk);
            #pragma unroll
            for (int nt = 0; nt < 4; ++nt)
                b[nt] = *(const bf16_8*)(Bs + (wn * 64 + nt * 16 + lrow) * LDKC + kk + lk);
            #pragma unroll
            for (int mt = 0; mt < 4; ++mt)
                #pragma unroll
                for (int nt = 0; nt < 4; ++nt)
                    acc[mt][nt] = __builtin_amdgcn_mfma_f32_16x16x32_bf16(
                        a[mt], b[nt], acc[mt][nt], 0, 0, 0);
        }
        __syncthreads();
    }

    bool isz = (n0 >= 256);
    __bf16* dst = isz ? z : xp;
    int ncol0 = isz ? n0 - 256 : n0;
    int row_base = (lane >> 4) * 4;
    int col = lane & 15;
    #pragma unroll
    for (int mt = 0; mt < 4; ++mt) {
        long mg = m0 + wm * 64 + mt * 16 + row_base;
        #pragma unroll
        for (int nt = 0; nt < 4; ++nt) {
            int ng = ncol0 + wn * 64 + nt * 16 + col;
            #pragma unroll
            for (int r = 0; r < 4; ++r)
                dst[(mg + r) * 256 + ng] = (__bf16)acc[mt][nt][r];
        }
    }
}

// ---------------------------------------------------------------------------
// SSM as per-batch Toeplitz MFMA GEMM, fused depthwise conv (in B staging) and
// sigmoid gate (in epilogue).  Y[l,c] = sum_j T[l,j]*Xc[j,c];  y = Y*sigmoid(z)
// written IN PLACE over z.  M=N=K=256 per batch; block = 128x128 tile.
#define LDB 72
__global__ __launch_bounds__(256) void ssm_gemm_kernel(const __bf16* __restrict__ xp,
                                                       __bf16* __restrict__ zy,
                                                       const __bf16* __restrict__ Tg,
                                                       const float* __restrict__ cw,
                                                       const float* __restrict__ cb) {
    __shared__ __bf16 As[128 * LDKC];
    __shared__ __bf16 Bs[128 * LDB];
    __shared__ float cws[128 * 4];
    __shared__ float cbs[128];
    int tid = threadIdx.x;
    int mtile = blockIdx.x >> 1, ntile = blockIdx.x & 1;
    int batch = blockIdx.y;
    int l0 = mtile * 128, c0 = ntile * 128;

    if (tid < 128) {
        *(float4*)(cws + tid * 4) = *(const float4*)(cw + (c0 + tid) * 4);
        cbs[tid] = cb[c0 + tid];
    }
    __syncthreads();

    int wave = tid >> 6, lane = tid & 63;
    int wm = wave >> 1, wn = wave & 1;
    int lrow = lane & 15, lk = (lane >> 4) * 8;
    f32_4 acc[4][4] = {};
    const __bf16* xb = xp + (long)batch * 65536;

    for (int kc = 0; kc < 4; ++kc) {
        int j0 = kc * 64;
        // A stage: T tile [l0..+127][j0..+63] = 1024 uint4 chunks (4 iters!)
        #pragma unroll
        for (int i = 0; i < 4; ++i) {
            int idx = tid + i * 256;          // 0..1023
            int row = idx >> 3, c4 = idx & 7; // 128 rows x 8 uint4
            uint4 v = *(const uint4*)(Tg + (l0 + row) * 256 + j0 + c4 * 8);
            *(uint4*)(As + row * LDKC + c4 * 8) = v;
        }
        // B stage: Xc^T tile [c][j]; conv(K=4) computed on the fly; transpose-
        // on-write (2B lanes consecutive -> 2-way bank aliasing, free)
        int j = tid & 63;
        int jj = j0 + j;
        #pragma unroll
        for (int cg = 0; cg < 4; ++cg) {
            int c = ((tid >> 6) * 4 + cg) * 8;
            const __bf16* bb = xb + c0 + c;
            bf16_8 zer = {};
            bf16_8 x0 = *(const bf16_8*)(bb + jj * 256);
            bf16_8 x1 = (jj >= 1) ? *(const bf16_8*)(bb + (jj - 1) * 256) : zer;
            bf16_8 x2 = (jj >= 2) ? *(const bf16_8*)(bb + (jj - 2) * 256) : zer;
            bf16_8 x3 = (jj >= 3) ? *(const bf16_8*)(bb + (jj - 3) * 256) : zer;
            #pragma unroll
            for (int i = 0; i < 8; ++i) {
                float4 w = *(float4*)(cws + (c + i) * 4);
                float xc = cbs[c + i] + w.x * (float)x3[i] + w.y * (float)x2[i]
                         + w.z * (float)x1[i] + w.w * (float)x0[i];
                Bs[(c + i) * LDB + j] = (__bf16)xc;
            }
        }
        __syncthreads();
        #pragma unroll
        for (int kk = 0; kk < 64; kk += 32) {
            bf16_8 a[4], b[4];
            #pragma unroll
            for (int mt = 0; mt < 4; ++mt)
                a[mt] = *(const bf16_8*)(As + (wm * 64 + mt * 16 + lrow) * LDKC + kk + lk);
            #pragma unroll
            for (int nt = 0; nt < 4; ++nt)
                b[nt] = *(const bf16_8*)(Bs + (wn * 64 + nt * 16 + lrow) * LDB + kk + lk);
            #pragma unroll
            for (int mt = 0; mt < 4; ++mt)
                #pragma unroll
                for (int nt = 0; nt < 4; ++nt)
                    acc[mt][nt] = __builtin_amdgcn_mfma_f32_16x16x32_bf16(
                        a[mt], b[nt], acc[mt][nt], 0, 0, 0);
        }
        __syncthreads();
    }

    // epilogue: gate with sigmoid(z), write y over z (each elem owned by 1 block)
    int row_base = (lane >> 4) * 4, col = lane & 15;
    #pragma unroll
    for (int mt = 0; mt < 4; ++mt) {
        int l = l0 + wm * 64 + mt * 16 + row_base;
        #pragma unroll
        for (int nt = 0; nt < 4; ++nt) {
            int cg = c0 + wn * 64 + nt * 16 + col;
            #pragma unroll
            for (int r = 0; r < 4; ++r) {
                long idx = (long)batch * 65536 + (long)(l + r) * 256 + cg;
                float zv = (float)zy[idx];
                float gate = 1.0f / (1.0f + expf(-zv));
                zy[idx] = (__bf16)(acc[mt][nt][r] * gate);
            }
        }
    }
}

// ---------------------------------------------------------------------------
// GEMM2 + residual: x[m,d] += clip(rs)*sum_c y[m,c]*Wout[d,c]; M=131072,N=128,K=256
__global__ __launch_bounds__(256) void gemm2_kernel(const __bf16* __restrict__ y,
                                                    const __bf16* __restrict__ wout,
                                                    float* __restrict__ x,
                                                    const float* __restrict__ rs_p) {
    __shared__ __bf16 As[128 * LDKC];
    __shared__ __bf16 Bs[128 * LDKC];
    int tid = threadIdx.x;
    long m0 = (long)blockIdx.x * 128;
    int wave = tid >> 6, lane = tid & 63;
    int wm = wave >> 1, wn = wave & 1;
    int lrow = lane & 15, lk = (lane >> 4) * 8;
    f32_4 acc[4][4] = {};

    for (int kc = 0; kc < 4; ++kc) {
        const __bf16* asrc = y + m0 * 256 + kc * 64;
        const __bf16* bsrc = wout + kc * 64;
        #pragma unroll
        for (int i = 0; i < 4; ++i) {
            int idx = tid + i * 256;
            int row = idx >> 3, c4 = idx & 7;
            uint4 va = *(const uint4*)(asrc + row * 256 + c4 * 8);
            *(uint4*)(As + row * LDKC + c4 * 8) = va;
            uint4 vb = *(const uint4*)(bsrc + row * 256 + c4 * 8);
            *(uint4*)(Bs + row * LDKC + c4 * 8) = vb;
        }
        __syncthreads();
        #pragma unroll
        for (int kk = 0; kk < 64; kk += 32) {
            bf16_8 a[4], b[4];
            #pragma unroll
            for (int mt = 0; mt < 4; ++mt)
                a[mt] = *(const bf16_8*)(As + (wm * 64 + mt * 16 + lrow) * LDKC + kk + lk);
            #pragma unroll
            for (int nt = 0; nt < 4; ++nt)
                b[nt] = *(const bf16_8*)(Bs + (wn * 64 + nt * 16 + lrow) * LDKC + kk + lk);
            #pragma unroll
            for (int mt = 0; mt < 4; ++mt)
                #pragma unroll
                for (int nt = 0; nt < 4; ++nt)
                    acc[mt][nt] = __builtin_amdgcn_mfma_f32_16x16x32_bf16(
                        a[mt], b[nt], acc[mt][nt], 0, 0, 0);
        }
        __syncthreads();
    }

    float rs = rs_p[0];
    rs = fminf(fmaxf(rs, 0.0f), 1.5f);
    int row_base = (lane >> 4) * 4;
    int col = lane & 15;
    #pragma unroll
    for (int mt = 0; mt < 4; ++mt) {
        long mg = m0 + wm * 64 + mt * 16 + row_base;
        #pragma unroll
        for (int nt = 0; nt < 4; ++nt) {
            int d = wn * 64 + nt * 16 + col;
            #pragma unroll
            for (int r = 0; r < 4; ++r) {
                long idx = (mg + r) * 128 + d;
                x[idx] = x[idx] + rs * acc[mt][nt][r];
            }
        }
    }
}

// ---------------------------------------------------------------------------
// Final LN -> tokens (fp32 output) + L2-normalized tn (bf16, workspace)
__global__ __launch_bounds__(256) void ln_final_kernel(const float* __restrict__ x,
                                                       const float* __restrict__ fg,
                                                       const float* __restrict__ fb,
                                                       float* __restrict__ tokens,
                                                       __bf16* __restrict__ tn) {
    int wave = threadIdx.x >> 6, lane = threadIdx.x & 63;
    long tok = (long)blockIdx.x * 4 + wave;
    const float* xr = x + tok * 128;
    float v0 = xr[lane], v1 = xr[lane + 64];
    float s = v0 + v1, ss = v0 * v0 + v1 * v1;
    #pragma unroll
    for (int o = 32; o; o >>= 1) { s += __shfl_xor(s, o); ss += __shfl_xor(ss, o); }
    float m = s * (1.0f / 128.0f);
    float var = ss * (1.0f / 128.0f) - m * m;
    float r = rsqrtf(var + 1e-5f);
    float t0 = (v0 - m) * r * fg[lane]      + fb[lane];
    float t1 = (v1 - m) * r * fg[lane + 64] + fb[lane + 64];
    tokens[tok * 128 + lane]      = t0;
    tokens[tok * 128 + lane + 64] = t1;
    float q = t0 * t0 + t1 * t1;
    #pragma unroll
    for (int o = 32; o; o >>= 1) q += __shfl_xor(q, o);
    float inv = 1.0f / fmaxf(sqrtf(q), 1e-6f);
    tn[tok * 128 + lane]      = (__bf16)(t0 * inv);
    tn[tok * 128 + lane + 64] = (__bf16)(t1 * inv);
}

// ---------------------------------------------------------------------------
// MLP via MFMA: logits[m] = gelu(tn[m,:] @ W1.T + b1) @ W2 + b2
// M=131072, N=64, K=128. Block: 128 tokens, 4 waves x 32 tokens.
#define LDA 136   // 128 + 8 pad (bf16 elems), row stride 272 B
__global__ __launch_bounds__(256) void mlp_kernel(const __bf16* __restrict__ tn,
                                                  const __bf16* __restrict__ w1b,
                                                  const float* __restrict__ b1,
                                                  const float* __restrict__ W2,
                                                  const float* __restrict__ b2,
                                                  float* __restrict__ logits) {
    __shared__ __bf16 As[128 * LDA];   // 34816 B
    __shared__ __bf16 Bs[64 * LDA];    // 17408 B
    int tid = threadIdx.x;
    long m0 = (long)blockIdx.x * 128;
    const __bf16* asrc = tn + m0 * 128;
    #pragma unroll
    for (int i = 0; i < 8; ++i) {
        int idx = tid + i * 256;           // 0..2047
        int row = idx >> 4, c = idx & 15;  // 16 uint4 per row
        uint4 v = *(const uint4*)(asrc + row * 128 + c * 8);
        *(uint4*)(As + row * LDA + c * 8) = v;
    }
    #pragma unroll
    for (int i = 0; i < 4; ++i) {
        int idx = tid + i * 256;
        int row = idx >> 4, c = idx & 15;
        uint4 v = *(const uint4*)(w1b + row * 128 + c * 8);
        *(uint4*)(Bs + row * LDA + c * 8) = v;
    }
    __syncthreads();

    int wave = tid >> 6, lane = tid & 63;
    int lrow = lane & 15, lk = (lane >> 4) * 8;
    f32_4 acc[2][4] = {};
    #pragma unroll
    for (int kk = 0; kk < 128; kk += 32) {
        bf16_8 a[2], b[4];
        #pragma unroll
        for (int mt = 0; mt < 2; ++mt)
            a[mt] = *(const bf16_8*)(As + (wave * 32 + mt * 16 + lrow) * LDA + kk + lk);
        #pragma unroll
        for (int nt = 0; nt < 4; ++nt)
            b[nt] = *(const bf16_8*)(Bs + (nt * 16 + lrow) * LDA + kk + lk);
        #pragma unroll
        for (int mt = 0; mt < 2; ++mt)
            #pragma unroll
            for (int nt = 0; nt < 4; ++nt)
                acc[mt][nt] = __builtin_amdgcn_mfma_f32_16x16x32_bf16(
                    a[mt], b[nt], acc[mt][nt], 0, 0, 0);
    }

    int col = lane & 15, quad = lane >> 4;
    float b2v = b2[0];
    #pragma unroll
    for (int mt = 0; mt < 2; ++mt) {
        #pragma unroll
        for (int r = 0; r < 4; ++r) {
            float p = 0.0f;
            #pragma unroll
            for (int nt = 0; nt < 4; ++nt) {
                int jx = nt * 16 + col;
                float a = acc[mt][nt][r] + b1[jx];
                float gl = 0.5f * a * (1.0f + erff(a * 0.70710678118654752f));
                p += gl * W2[jx];
            }
            #pragma unroll
            for (int o = 8; o; o >>= 1) p += __shfl_xor(p, o);
            if (col == 0) {
                long tok = m0 + wave * 32 + mt * 16 + quad * 4 + r;
                logits[tok] = p + b2v;
            }
        }
    }
}

// ---------------------------------------------------------------------------
// Per-batch softmax over L, feats = sum_l w_l * tokens, 3 small head linears
__global__ __launch_bounds__(256) void head_kernel(const float* __restrict__ tokens,
                                                   const float* __restrict__ logits,
                                                   const float* __restrict__ texW,
                                                   const float* __restrict__ texb,
                                                   const float* __restrict__ edgeW,
                                                   const float* __restrict__ edgeb,
                                                   const float* __restrict__ strW,
                                                   const float* __restrict__ strb,
                                                   float* __restrict__ feats_out,
                                                   float* __restrict__ tex_out,
                                                   float* __restrict__ edge_out,
                                                   float* __restrict__ str_out,
                                                   float* __restrict__ w_out) {
    __shared__ float wsm[256];
    __shared__ float red[8];
    __shared__ float feats_s[128];
    int b = blockIdx.x, tid = threadIdx.x;
    int lane = tid & 63, wave = tid >> 6;
    float lg = logits[(long)b * 256 + tid];
    float mx = lg;
    #pragma unroll
    for (int o = 32; o; o >>= 1) mx = fmaxf(mx, __shfl_xor(mx, o));
    if (lane == 0) red[wave] = mx;
    __syncthreads();
    float bm = fmaxf(fmaxf(red[0], red[1]), fmaxf(red[2], red[3]));
    float e = expf(lg - bm);
    float se = e;
    #pragma unroll
    for (int o = 32; o; o >>= 1) se += __shfl_xor(se, o);
    if (lane == 0) red[4 + wave] = se;
    __syncthreads();
    float tot = red[4] + red[5] + red[6] + red[7];
    float w = e / tot;
    wsm[tid] = w;
    w_out[(long)b * 256 + tid] = w;
    __syncthreads();
    if (tid < 128) {
        float acc = 0.0f;
        const float* tb = tokens + (long)b * 256 * 128 + tid;
        #pragma unroll 4
        for (int l = 0; l < 256; ++l) acc += tb[l * 128] * wsm[l];
        feats_s[tid] = acc;
        feats_out[(long)b * 128 + tid] = acc;
    }
    __syncthreads();
    if (tid < 192) {
        int head = tid >> 6, j = tid & 63;
        const float* W  = head == 0 ? texW : (head == 1 ? edgeW : strW);
        const float* bi = head == 0 ? texb : (head == 1 ? edgeb : strb);
        float* outp     = head == 0 ? tex_out : (head == 1 ? edge_out : str_out);
        const float* wr = W + j * 128;
        float acc = 0.0f;
        #pragma unroll 8
        for (int k = 0; k < 128; ++k) acc += feats_s[k] * wr[k];
        outp[(long)b * 64 + j] = acc + bi[j];
    }
}

// ---------------------------------------------------------------------------
extern "C" void kernel_launch(void* const* d_in, const int* in_sizes, int n_in,
                              void* d_out, int out_size, void* d_ws, size_t ws_size,
                              hipStream_t stream) {
    const float* init   = (const float*)d_in[0];
    const float* pos    = (const float*)d_in[1];
    const float* ln_g   = (const float*)d_in[2];
    const float* ln_b   = (const float*)d_in[3];
    const float* W_in   = (const float*)d_in[4];
    const float* conv_w = (const float*)d_in[5];
    const float* conv_b = (const float*)d_in[6];
    const float* ssm_B  = (const float*)d_in[7];
    const float* ssm_C  = (const float*)d_in[8];
    const float* log_dt = (const float*)d_in[9];
    const float* ssm_D  = (const float*)d_in[10];
    const float* W_out  = (const float*)d_in[11];
    const float* res_sc = (const float*)d_in[12];
    const float* fin_g  = (const float*)d_in[13];
    const float* fin_b  = (const float*)d_in[14];
    const float* imp_W1 = (const float*)d_in[15];
    const float* imp_b1 = (const float*)d_in[16];
    const float* imp_W2 = (const float*)d_in[17];
    const float* imp_b2 = (const float*)d_in[18];
    const float* tex_W  = (const float*)d_in[19];
    const float* tex_b  = (const float*)d_in[20];
    const float* edge_W = (const float*)d_in[21];
    const float* edge_b = (const float*)d_in[22];
    const float* str_W  = (const float*)d_in[23];
    const float* str_b  = (const float*)d_in[24];

    float* out = (float*)d_out;
    char* ws = (char*)d_ws;
    float*  x      = (float*)ws;                      // 67108864 B  (M*D fp32)
    __bf16* xpb    = (__bf16*)(ws + 67108864);        // 67108864 B  (M*DI bf16)
    __bf16* zb     = (__bf16*)(ws + 134217728);       // 67108864 B  (z; y in place)
    __bf16* hb     = (__bf16*)(ws + 201326592);       // 33554432 B  (M*D bf16; reused as tn)
    __bf16* win16  = (__bf16*)(ws + 234881024);       // 524288 B
    __bf16* wout16 = (__bf16*)(ws + 235405312);       // 262144 B
    float*  logits = (float*)(ws + 235667456);        // 524288 B
    __bf16* w1b    = (__bf16*)(ws + 236191744);       // 16384 B
    __bf16* Tg     = (__bf16*)(ws + 236208128);       // 524288 B (4 layers x 256x256 bf16)

    prep_kernel<<<1024, 256, 0, stream>>>(W_in, W_out, imp_W1, win16, wout16, w1b);
    build_T_kernel<<<dim3(256, 4), 256, 0, stream>>>(ssm_B, ssm_C, log_dt, ssm_D, Tg);
    add_pos_kernel<<<16384, 256, 0, stream>>>((const float4*)init, (const float4*)pos,
                                              (float4*)x);
    for (int l = 0; l < 4; ++l) {
        ln_kernel<<<32768, 256, 0, stream>>>(x, ln_g + l * 128, ln_b + l * 128, hb);
        gemm1_kernel<<<dim3(1024, 4), 256, 0, stream>>>(hb, win16 + l * 65536, xpb, zb);
        ssm_gemm_kernel<<<dim3(4, 512), 256, 0, stream>>>(xpb, zb, Tg + l * 65536,
                                                          conv_w + l * 1024,
                                                          conv_b + l * 256);
        gemm2_kernel<<<1024, 256, 0, stream>>>(zb, wout16 + l * 32768, x, res_sc + l);
    }
    float* tokens = out + 163840;
    __bf16* tn = hb;  // reuse: hb is dead after the layer loop
    ln_final_kernel<<<32768, 256, 0, stream>>>(x, fin_g, fin_b, tokens, tn);
    mlp_kernel<<<1024, 256, 0, stream>>>(tn, w1b, imp_b1, imp_W2, imp_b2, logits);
    head_kernel<<<512, 256, 0, stream>>>(tokens, logits, tex_W, tex_b, edge_W, edge_b,
                                         str_W, str_b, out, out + 65536, out + 98304,
                                         out + 131072, out + 16941056);
}

// Round 5
// 1056.425 us; speedup vs baseline: 1.1076x; 1.1076x over previous
//
#include <hip/hip_runtime.h>
#include <hip/hip_bf16.h>

// Problem constants
// B=512, N(L)=256, D=128, DI=256, NL=4, NS=16, KC=4, DH=64, H=64
// M = B*N = 131072 tokens

typedef __bf16 bf16_8 __attribute__((ext_vector_type(8)));
typedef __bf16 bf16_4 __attribute__((ext_vector_type(4)));
typedef float  f32_4  __attribute__((ext_vector_type(4)));

#define LDKC 72   // 64 K-chunk + 8 pad (row stride 144B, multiple of 16B)

// ---------------------------------------------------------------------------
// prep: convert W_in (4*512*128), W_out (4*128*256), imp_W1 (64*128) fp32->bf16
__global__ __launch_bounds__(256) void prep_kernel(const float* __restrict__ win,
                                                   const float* __restrict__ wout,
                                                   const float* __restrict__ w1,
                                                   __bf16* __restrict__ win16,
                                                   __bf16* __restrict__ wout16,
                                                   __bf16* __restrict__ w116) {
    int i = blockIdx.x * 256 + threadIdx.x;
    if (i < 4 * 512 * 128) win16[i] = (__bf16)win[i];
    if (i < 4 * 128 * 256) wout16[i] = (__bf16)wout[i];
    if (i < 64 * 128)      w116[i]  = (__bf16)w1[i];
}

// ---------------------------------------------------------------------------
// build_T: T[layer][l][j] = Kk[l-j] + (l==j)*Dp, 0 for j>l  (bf16, 256x256/layer)
__global__ __launch_bounds__(256) void build_T_kernel(const float* __restrict__ Bp,
                                                      const float* __restrict__ Cp,
                                                      const float* __restrict__ ldt,
                                                      const float* __restrict__ Dpv,
                                                      __bf16* __restrict__ Tg) {
    int layer = blockIdx.y, l = blockIdx.x, j = threadIdx.x;
    int d = l - j;
    float val = 0.0f;
    if (d >= 0) {
        float dt = expf(ldt[layer]);
        dt = fminf(fmaxf(dt, 1e-4f), 1.0f);
        #pragma unroll
        for (int n = 0; n < 16; ++n) {
            float A = -(float)(n + 1);
            float e = fminf(fmaxf(dt * A, -10.0f), 10.0f);
            float dA = expf(e);
            float dB = (dA - 1.0f) / A * Bp[layer * 16 + n];
            val += Cp[layer * 16 + n] * dB * expf(e * (float)d);
        }
        if (d == 0) val += Dpv[layer];
    }
    Tg[layer * 65536 + l * 256 + j] = (__bf16)val;
}

// ---------------------------------------------------------------------------
// x = init + pos (broadcast over batch)
__global__ __launch_bounds__(256) void add_pos_kernel(const float4* __restrict__ a,
                                                      const float4* __restrict__ p,
                                                      float4* __restrict__ x) {
    int i = blockIdx.x * 256 + threadIdx.x;       // 4194304 total float4
    float4 u = a[i];
    float4 v = p[i & 8191];                       // N*D/4 = 8192 per batch
    x[i] = make_float4(u.x + v.x, u.y + v.y, u.z + v.z, u.w + v.w);
}

// ---------------------------------------------------------------------------
// LayerNorm: x fp32 -> h bf16.  One wave per token (D=128, 2 elems/lane).
__global__ __launch_bounds__(256) void ln_kernel(const float* __restrict__ x,
                                                 const float* __restrict__ g,
                                                 const float* __restrict__ bta,
                                                 __bf16* __restrict__ h) {
    int wave = threadIdx.x >> 6, lane = threadIdx.x & 63;
    long tok = (long)blockIdx.x * 4 + wave;
    const float* xr = x + tok * 128;
    float v0 = xr[lane], v1 = xr[lane + 64];
    float s = v0 + v1, ss = v0 * v0 + v1 * v1;
    #pragma unroll
    for (int o = 32; o; o >>= 1) { s += __shfl_xor(s, o); ss += __shfl_xor(ss, o); }
    float m = s * (1.0f / 128.0f);
    float var = ss * (1.0f / 128.0f) - m * m;
    float r = rsqrtf(var + 1e-5f);
    __bf16* hr = h + tok * 128;
    hr[lane]      = (__bf16)((v0 - m) * r * g[lane]      + bta[lane]);
    hr[lane + 64] = (__bf16)((v1 - m) * r * g[lane + 64] + bta[lane + 64]);
}

// ---------------------------------------------------------------------------
// GEMM1: xz[m,n] = sum_k h[m,k] * Win[n,k]; M=131072, N=512, K=128.
// xp written TRANSPOSED: xpt[b][n][l] (so conv + SSM-GEMM staging are coalesced);
// z written in [m][c] layout.
__global__ __launch_bounds__(256) void gemm1_kernel(const __bf16* __restrict__ hmat,
                                                    const __bf16* __restrict__ win,
                                                    __bf16* __restrict__ xpt,
                                                    __bf16* __restrict__ z) {
    __shared__ __bf16 As[128 * LDKC];
    __shared__ __bf16 Bs[128 * LDKC];
    int tid = threadIdx.x;
    long m0 = (long)blockIdx.x * 128;
    int n0 = blockIdx.y * 128;
    int wave = tid >> 6, lane = tid & 63;
    int wm = wave >> 1, wn = wave & 1;
    int lrow = lane & 15, lk = (lane >> 4) * 8;
    f32_4 acc[4][4] = {};

    for (int kc = 0; kc < 2; ++kc) {
        const __bf16* asrc = hmat + m0 * 128 + kc * 64;
        const __bf16* bsrc = win + (long)n0 * 128 + kc * 64;
        #pragma unroll
        for (int i = 0; i < 4; ++i) {
            int idx = tid + i * 256;          // 0..1023
            int row = idx >> 3, c4 = idx & 7; // 8 uint4 per 64-elem row
            uint4 va = *(const uint4*)(asrc + row * 128 + c4 * 8);
            *(uint4*)(As + row * LDKC + c4 * 8) = va;
            uint4 vb = *(const uint4*)(bsrc + row * 128 + c4 * 8);
            *(uint4*)(Bs + row * LDKC + c4 * 8) = vb;
        }
        __syncthreads();
        #pragma unroll
        for (int kk = 0; kk < 64; kk += 32) {
            bf16_8 a[4], b[4];
            #pragma unroll
            for (int mt = 0; mt < 4; ++mt)
                a[mt] = *(const bf16_8*)(As + (wm * 64 + mt * 16 + lrow) * LDKC + kk + lk);
            #pragma unroll
            for (int nt = 0; nt < 4; ++nt)
                b[nt] = *(const bf16_8*)(Bs + (wn * 64 + nt * 16 + lrow) * LDKC + kk + lk);
            #pragma unroll
            for (int mt = 0; mt < 4; ++mt)
                #pragma unroll
                for (int nt = 0; nt < 4; ++nt)
                    acc[mt][nt] = __builtin_amdgcn_mfma_f32_16x16x32_bf16(
                        a[mt], b[nt], acc[mt][nt], 0, 0, 0);
        }
        __syncthreads();
    }

    int row_base = (lane >> 4) * 4;
    int col = lane & 15;
    if (n0 < 256) {
        // xp branch: transposed packed write xpt[b][n][l..l+3]
        #pragma unroll
        for (int mt = 0; mt < 4; ++mt) {
            long mg = m0 + wm * 64 + mt * 16 + row_base;
            int b = (int)(mg >> 8), l = (int)(mg & 255);  // l multiple of 4 -> 8B aligned
            #pragma unroll
            for (int nt = 0; nt < 4; ++nt) {
                int ng = n0 + wn * 64 + nt * 16 + col;
                bf16_4 o;
                #pragma unroll
                for (int r = 0; r < 4; ++r) o[r] = (__bf16)acc[mt][nt][r];
                *(bf16_4*)(xpt + (long)b * 65536 + (long)ng * 256 + l) = o;
            }
        }
    } else {
        int ncol0 = n0 - 256;
        #pragma unroll
        for (int mt = 0; mt < 4; ++mt) {
            long mg = m0 + wm * 64 + mt * 16 + row_base;
            #pragma unroll
            for (int nt = 0; nt < 4; ++nt) {
                int ng = ncol0 + wn * 64 + nt * 16 + col;
                #pragma unroll
                for (int r = 0; r < 4; ++r)
                    z[(mg + r) * 256 + ng] = (__bf16)acc[mt][nt][r];
            }
        }
    }
}

// ---------------------------------------------------------------------------
// Depthwise causal conv (K=4) IN PLACE on xpt[b][c][l] (contiguous along l).
// One wave per row; all wave loads complete before stores -> race-free.
__global__ __launch_bounds__(256) void conv_t_kernel(__bf16* __restrict__ xpt,
                                                     const float* __restrict__ cw,
                                                     const float* __restrict__ cb) {
    int wave = threadIdx.x >> 6, lane = threadIdx.x & 63;
    int row = blockIdx.x * 4 + wave;          // row = b*256 + c, 131072 rows
    int c = row & 255;
    float w0 = cw[c * 4 + 0], w1 = cw[c * 4 + 1], w2 = cw[c * 4 + 2], w3 = cw[c * 4 + 3];
    float bias = cb[c];
    __bf16* rp = xpt + (long)row * 256;
    int j0 = lane * 4;
    bf16_4 cur = *(const bf16_4*)(rp + j0);
    bf16_4 prv = {};
    if (j0 >= 4) prv = *(const bf16_4*)(rp + j0 - 4);
    float xm3 = (float)prv[1], xm2 = (float)prv[2], xm1 = (float)prv[3];
    float x0 = (float)cur[0], x1 = (float)cur[1], x2 = (float)cur[2], x3 = (float)cur[3];
    bf16_4 o;
    o[0] = (__bf16)(bias + w0 * xm3 + w1 * xm2 + w2 * xm1 + w3 * x0);
    o[1] = (__bf16)(bias + w0 * xm2 + w1 * xm1 + w2 * x0  + w3 * x1);
    o[2] = (__bf16)(bias + w0 * xm1 + w1 * x0  + w2 * x1  + w3 * x2);
    o[3] = (__bf16)(bias + w0 * x0  + w1 * x1  + w2 * x2  + w3 * x3);
    *(bf16_4*)(rp + j0) = o;
}

// ---------------------------------------------------------------------------
// SSM as per-batch Toeplitz MFMA GEMM.  Y[l,c] = sum_j T[l,j]*Xc^T[c,j];
// y = Y*sigmoid(z) written IN PLACE over z.  Both operands uint4-staged.
__global__ __launch_bounds__(256) void ssm_gemm_kernel(const __bf16* __restrict__ xct,
                                                       __bf16* __restrict__ zy,
                                                       const __bf16* __restrict__ Tg) {
    __shared__ __bf16 As[128 * LDKC];
    __shared__ __bf16 Bs[128 * LDKC];
    int tid = threadIdx.x;
    int mtile = blockIdx.x >> 1, ntile = blockIdx.x & 1;
    int batch = blockIdx.y;
    int l0 = mtile * 128, c0 = ntile * 128;

    int wave = tid >> 6, lane = tid & 63;
    int wm = wave >> 1, wn = wave & 1;
    int lrow = lane & 15, lk = (lane >> 4) * 8;
    f32_4 acc[4][4] = {};
    const __bf16* bsrc0 = xct + (long)batch * 65536 + (long)c0 * 256;

    for (int kc = 0; kc < 4; ++kc) {
        int j0 = kc * 64;
        #pragma unroll
        for (int i = 0; i < 4; ++i) {
            int idx = tid + i * 256;          // 0..1023
            int row = idx >> 3, c4 = idx & 7; // 128 rows x 8 uint4
            uint4 va = *(const uint4*)(Tg + (l0 + row) * 256 + j0 + c4 * 8);
            *(uint4*)(As + row * LDKC + c4 * 8) = va;
            uint4 vb = *(const uint4*)(bsrc0 + (long)row * 256 + j0 + c4 * 8);
            *(uint4*)(Bs + row * LDKC + c4 * 8) = vb;
        }
        __syncthreads();
        #pragma unroll
        for (int kk = 0; kk < 64; kk += 32) {
            bf16_8 a[4], b[4];
            #pragma unroll
            for (int mt = 0; mt < 4; ++mt)
                a[mt] = *(const bf16_8*)(As + (wm * 64 + mt * 16 + lrow) * LDKC + kk + lk);
            #pragma unroll
            for (int nt = 0; nt < 4; ++nt)
                b[nt] = *(const bf16_8*)(Bs + (wn * 64 + nt * 16 + lrow) * LDKC + kk + lk);
            #pragma unroll
            for (int mt = 0; mt < 4; ++mt)
                #pragma unroll
                for (int nt = 0; nt < 4; ++nt)
                    acc[mt][nt] = __builtin_amdgcn_mfma_f32_16x16x32_bf16(
                        a[mt], b[nt], acc[mt][nt], 0, 0, 0);
        }
        __syncthreads();
    }

    // epilogue: gate with sigmoid(z), write y over z (each elem owned by 1 block)
    int row_base = (lane >> 4) * 4, col = lane & 15;
    #pragma unroll
    for (int mt = 0; mt < 4; ++mt) {
        int l = l0 + wm * 64 + mt * 16 + row_base;
        #pragma unroll
        for (int nt = 0; nt < 4; ++nt) {
            int cg = c0 + wn * 64 + nt * 16 + col;
            #pragma unroll
            for (int r = 0; r < 4; ++r) {
                long idx = (long)batch * 65536 + (long)(l + r) * 256 + cg;
                float zv = (float)zy[idx];
                float gate = 1.0f / (1.0f + expf(-zv));
                zy[idx] = (__bf16)(acc[mt][nt][r] * gate);
            }
        }
    }
}

// ---------------------------------------------------------------------------
// GEMM2 + residual: x[m,d] += clip(rs)*sum_c y[m,c]*Wout[d,c]; M=131072,N=128,K=256
__global__ __launch_bounds__(256) void gemm2_kernel(const __bf16* __restrict__ y,
                                                    const __bf16* __restrict__ wout,
                                                    float* __restrict__ x,
                                                    const float* __restrict__ rs_p) {
    __shared__ __bf16 As[128 * LDKC];
    __shared__ __bf16 Bs[128 * LDKC];
    int tid = threadIdx.x;
    long m0 = (long)blockIdx.x * 128;
    int wave = tid >> 6, lane = tid & 63;
    int wm = wave >> 1, wn = wave & 1;
    int lrow = lane & 15, lk = (lane >> 4) * 8;
    f32_4 acc[4][4] = {};

    for (int kc = 0; kc < 4; ++kc) {
        const __bf16* asrc = y + m0 * 256 + kc * 64;
        const __bf16* bsrc = wout + kc * 64;
        #pragma unroll
        for (int i = 0; i < 4; ++i) {
            int idx = tid + i * 256;
            int row = idx >> 3, c4 = idx & 7;
            uint4 va = *(const uint4*)(asrc + row * 256 + c4 * 8);
            *(uint4*)(As + row * LDKC + c4 * 8) = va;
            uint4 vb = *(const uint4*)(bsrc + row * 256 + c4 * 8);
            *(uint4*)(Bs + row * LDKC + c4 * 8) = vb;
        }
        __syncthreads();
        #pragma unroll
        for (int kk = 0; kk < 64; kk += 32) {
            bf16_8 a[4], b[4];
            #pragma unroll
            for (int mt = 0; mt < 4; ++mt)
                a[mt] = *(const bf16_8*)(As + (wm * 64 + mt * 16 + lrow) * LDKC + kk + lk);
            #pragma unroll
            for (int nt = 0; nt < 4; ++nt)
                b[nt] = *(const bf16_8*)(Bs + (wn * 64 + nt * 16 + lrow) * LDKC + kk + lk);
            #pragma unroll
            for (int mt = 0; mt < 4; ++mt)
                #pragma unroll
                for (int nt = 0; nt < 4; ++nt)
                    acc[mt][nt] = __builtin_amdgcn_mfma_f32_16x16x32_bf16(
                        a[mt], b[nt], acc[mt][nt], 0, 0, 0);
        }
        __syncthreads();
    }

    float rs = rs_p[0];
    rs = fminf(fmaxf(rs, 0.0f), 1.5f);
    int row_base = (lane >> 4) * 4;
    int col = lane & 15;
    #pragma unroll
    for (int mt = 0; mt < 4; ++mt) {
        long mg = m0 + wm * 64 + mt * 16 + row_base;
        #pragma unroll
        for (int nt = 0; nt < 4; ++nt) {
            int d = wn * 64 + nt * 16 + col;
            #pragma unroll
            for (int r = 0; r < 4; ++r) {
                long idx = (mg + r) * 128 + d;
                x[idx] = x[idx] + rs * acc[mt][nt][r];
            }
        }
    }
}

// ---------------------------------------------------------------------------
// Final LN -> tokens (fp32 output) + L2-normalized tn (bf16, workspace)
__global__ __launch_bounds__(256) void ln_final_kernel(const float* __restrict__ x,
                                                       const float* __restrict__ fg,
                                                       const float* __restrict__ fb,
                                                       float* __restrict__ tokens,
                                                       __bf16* __restrict__ tn) {
    int wave = threadIdx.x >> 6, lane = threadIdx.x & 63;
    long tok = (long)blockIdx.x * 4 + wave;
    const float* xr = x + tok * 128;
    float v0 = xr[lane], v1 = xr[lane + 64];
    float s = v0 + v1, ss = v0 * v0 + v1 * v1;
    #pragma unroll
    for (int o = 32; o; o >>= 1) { s += __shfl_xor(s, o); ss += __shfl_xor(ss, o); }
    float m = s * (1.0f / 128.0f);
    float var = ss * (1.0f / 128.0f) - m * m;
    float r = rsqrtf(var + 1e-5f);
    float t0 = (v0 - m) * r * fg[lane]      + fb[lane];
    float t1 = (v1 - m) * r * fg[lane + 64] + fb[lane + 64];
    tokens[tok * 128 + lane]      = t0;
    tokens[tok * 128 + lane + 64] = t1;
    float q = t0 * t0 + t1 * t1;
    #pragma unroll
    for (int o = 32; o; o >>= 1) q += __shfl_xor(q, o);
    float inv = 1.0f / fmaxf(sqrtf(q), 1e-6f);
    tn[tok * 128 + lane]      = (__bf16)(t0 * inv);
    tn[tok * 128 + lane + 64] = (__bf16)(t1 * inv);
}

// ---------------------------------------------------------------------------
// MLP via MFMA: logits[m] = gelu(tn[m,:] @ W1.T + b1) @ W2 + b2
#define LDA 136   // 128 + 8 pad (bf16 elems), row stride 272 B
__global__ __launch_bounds__(256) void mlp_kernel(const __bf16* __restrict__ tn,
                                                  const __bf16* __restrict__ w1b,
                                                  const float* __restrict__ b1,
                                                  const float* __restrict__ W2,
                                                  const float* __restrict__ b2,
                                                  float* __restrict__ logits) {
    __shared__ __bf16 As[128 * LDA];   // 34816 B
    __shared__ __bf16 Bs[64 * LDA];    // 17408 B
    int tid = threadIdx.x;
    long m0 = (long)blockIdx.x * 128;
    const __bf16* asrc = tn + m0 * 128;
    #pragma unroll
    for (int i = 0; i < 8; ++i) {
        int idx = tid + i * 256;           // 0..2047
        int row = idx >> 4, c = idx & 15;  // 16 uint4 per row
        uint4 v = *(const uint4*)(asrc + row * 128 + c * 8);
        *(uint4*)(As + row * LDA + c * 8) = v;
    }
    #pragma unroll
    for (int i = 0; i < 4; ++i) {
        int idx = tid + i * 256;
        int row = idx >> 4, c = idx & 15;
        uint4 v = *(const uint4*)(w1b + row * 128 + c * 8);
        *(uint4*)(Bs + row * LDA + c * 8) = v;
    }
    __syncthreads();

    int wave = tid >> 6, lane = tid & 63;
    int lrow = lane & 15, lk = (lane >> 4) * 8;
    f32_4 acc[2][4] = {};
    #pragma unroll
    for (int kk = 0; kk < 128; kk += 32) {
        bf16_8 a[2], b[4];
        #pragma unroll
        for (int mt = 0; mt < 2; ++mt)
            a[mt] = *(const bf16_8*)(As + (wave * 32 + mt * 16 + lrow) * LDA + kk + lk);
        #pragma unroll
        for (int nt = 0; nt < 4; ++nt)
            b[nt] = *(const bf16_8*)(Bs + (nt * 16 + lrow) * LDA + kk + lk);
        #pragma unroll
        for (int mt = 0; mt < 2; ++mt)
            #pragma unroll
            for (int nt = 0; nt < 4; ++nt)
                acc[mt][nt] = __builtin_amdgcn_mfma_f32_16x16x32_bf16(
                    a[mt], b[nt], acc[mt][nt], 0, 0, 0);
    }

    int col = lane & 15, quad = lane >> 4;
    float b2v = b2[0];
    #pragma unroll
    for (int mt = 0; mt < 2; ++mt) {
        #pragma unroll
        for (int r = 0; r < 4; ++r) {
            float p = 0.0f;
            #pragma unroll
            for (int nt = 0; nt < 4; ++nt) {
                int jx = nt * 16 + col;
                float a = acc[mt][nt][r] + b1[jx];
                float gl = 0.5f * a * (1.0f + erff(a * 0.70710678118654752f));
                p += gl * W2[jx];
            }
            #pragma unroll
            for (int o = 8; o; o >>= 1) p += __shfl_xor(p, o);
            if (col == 0) {
                long tok = m0 + wave * 32 + mt * 16 + quad * 4 + r;
                logits[tok] = p + b2v;
            }
        }
    }
}

// ---------------------------------------------------------------------------
// Per-batch softmax over L, feats = sum_l w_l * tokens, 3 small head linears
__global__ __launch_bounds__(256) void head_kernel(const float* __restrict__ tokens,
                                                   const float* __restrict__ logits,
                                                   const float* __restrict__ texW,
                                                   const float* __restrict__ texb,
                                                   const float* __restrict__ edgeW,
                                                   const float* __restrict__ edgeb,
                                                   const float* __restrict__ strW,
                                                   const float* __restrict__ strb,
                                                   float* __restrict__ feats_out,
                                                   float* __restrict__ tex_out,
                                                   float* __restrict__ edge_out,
                                                   float* __restrict__ str_out,
                                                   float* __restrict__ w_out) {
    __shared__ float wsm[256];
    __shared__ float red[8];
    __shared__ float feats_s[128];
    int b = blockIdx.x, tid = threadIdx.x;
    int lane = tid & 63, wave = tid >> 6;
    float lg = logits[(long)b * 256 + tid];
    float mx = lg;
    #pragma unroll
    for (int o = 32; o; o >>= 1) mx = fmaxf(mx, __shfl_xor(mx, o));
    if (lane == 0) red[wave] = mx;
    __syncthreads();
    float bm = fmaxf(fmaxf(red[0], red[1]), fmaxf(red[2], red[3]));
    float e = expf(lg - bm);
    float se = e;
    #pragma unroll
    for (int o = 32; o; o >>= 1) se += __shfl_xor(se, o);
    if (lane == 0) red[4 + wave] = se;
    __syncthreads();
    float tot = red[4] + red[5] + red[6] + red[7];
    float w = e / tot;
    wsm[tid] = w;
    w_out[(long)b * 256 + tid] = w;
    __syncthreads();
    if (tid < 128) {
        float acc = 0.0f;
        const float* tb = tokens + (long)b * 256 * 128 + tid;
        #pragma unroll 4
        for (int l = 0; l < 256; ++l) acc += tb[l * 128] * wsm[l];
        feats_s[tid] = acc;
        feats_out[(long)b * 128 + tid] = acc;
    }
    __syncthreads();
    if (tid < 192) {
        int head = tid >> 6, j = tid & 63;
        const float* W  = head == 0 ? texW : (head == 1 ? edgeW : strW);
        const float* bi = head == 0 ? texb : (head == 1 ? edgeb : strb);
        float* outp     = head == 0 ? tex_out : (head == 1 ? edge_out : str_out);
        const float* wr = W + j * 128;
        float acc = 0.0f;
        #pragma unroll 8
        for (int k = 0; k < 128; ++k) acc += feats_s[k] * wr[k];
        outp[(long)b * 64 + j] = acc + bi[j];
    }
}

// ---------------------------------------------------------------------------
extern "C" void kernel_launch(void* const* d_in, const int* in_sizes, int n_in,
                              void* d_out, int out_size, void* d_ws, size_t ws_size,
                              hipStream_t stream) {
    const float* init   = (const float*)d_in[0];
    const float* pos    = (const float*)d_in[1];
    const float* ln_g   = (const float*)d_in[2];
    const float* ln_b   = (const float*)d_in[3];
    const float* W_in   = (const float*)d_in[4];
    const float* conv_w = (const float*)d_in[5];
    const float* conv_b = (const float*)d_in[6];
    const float* ssm_B  = (const float*)d_in[7];
    const float* ssm_C  = (const float*)d_in[8];
    const float* log_dt = (const float*)d_in[9];
    const float* ssm_D  = (const float*)d_in[10];
    const float* W_out  = (const float*)d_in[11];
    const float* res_sc = (const float*)d_in[12];
    const float* fin_g  = (const float*)d_in[13];
    const float* fin_b  = (const float*)d_in[14];
    const float* imp_W1 = (const float*)d_in[15];
    const float* imp_b1 = (const float*)d_in[16];
    const float* imp_W2 = (const float*)d_in[17];
    const float* imp_b2 = (const float*)d_in[18];
    const float* tex_W  = (const float*)d_in[19];
    const float* tex_b  = (const float*)d_in[20];
    const float* edge_W = (const float*)d_in[21];
    const float* edge_b = (const float*)d_in[22];
    const float* str_W  = (const float*)d_in[23];
    const float* str_b  = (const float*)d_in[24];

    float* out = (float*)d_out;
    char* ws = (char*)d_ws;
    float*  x      = (float*)ws;                      // 67108864 B  (M*D fp32)
    __bf16* xpt    = (__bf16*)(ws + 67108864);        // 67108864 B  (xp transposed [b][c][l])
    __bf16* zb     = (__bf16*)(ws + 134217728);       // 67108864 B  (z; y in place)
    __bf16* hb     = (__bf16*)(ws + 201326592);       // 33554432 B  (M*D bf16; reused as tn)
    __bf16* win16  = (__bf16*)(ws + 234881024);       // 524288 B
    __bf16* wout16 = (__bf16*)(ws + 235405312);       // 262144 B
    float*  logits = (float*)(ws + 235667456);        // 524288 B
    __bf16* w1b    = (__bf16*)(ws + 236191744);       // 16384 B
    __bf16* Tg     = (__bf16*)(ws + 236208128);       // 524288 B (4 layers x 256x256 bf16)

    prep_kernel<<<1024, 256, 0, stream>>>(W_in, W_out, imp_W1, win16, wout16, w1b);
    build_T_kernel<<<dim3(256, 4), 256, 0, stream>>>(ssm_B, ssm_C, log_dt, ssm_D, Tg);
    add_pos_kernel<<<16384, 256, 0, stream>>>((const float4*)init, (const float4*)pos,
                                              (float4*)x);
    for (int l = 0; l < 4; ++l) {
        ln_kernel<<<32768, 256, 0, stream>>>(x, ln_g + l * 128, ln_b + l * 128, hb);
        gemm1_kernel<<<dim3(1024, 4), 256, 0, stream>>>(hb, win16 + l * 65536, xpt, zb);
        conv_t_kernel<<<32768, 256, 0, stream>>>(xpt, conv_w + l * 1024, conv_b + l * 256);
        ssm_gemm_kernel<<<dim3(4, 512), 256, 0, stream>>>(xpt, zb, Tg + l * 65536);
        gemm2_kernel<<<1024, 256, 0, stream>>>(zb, wout16 + l * 32768, x, res_sc + l);
    }
    float* tokens = out + 163840;
    __bf16* tn = hb;  // reuse: hb is dead after the layer loop
    ln_final_kernel<<<32768, 256, 0, stream>>>(x, fin_g, fin_b, tokens, tn);
    mlp_kernel<<<1024, 256, 0, stream>>>(tn, w1b, imp_b1, imp_W2, imp_b2, logits);
    head_kernel<<<512, 256, 0, stream>>>(tokens, logits, tex_W, tex_b, edge_W, edge_b,
                                         str_W, str_b, out, out + 65536, out + 98304,
                                         out + 131072, out + 16941056);
}